// Round 3
// baseline (215.412 us; speedup 1.0000x reference)
//
#include <hip/hip_runtime.h>

#define PHH 7
#define PWW 7
static constexpr float SPATIAL_SCALE = 0.0625f;

// Antiderivative of hat function phi(t) = max(0, 1-|t|), saturating to [0,1].
__device__ __forceinline__ float hat_int(float t) {
    t = fminf(fmaxf(t, -1.0f), 1.0f);
    float a = t + 1.0f, b = 1.0f - t;
    return (t <= 0.0f) ? 0.5f * a * a : 1.0f - 0.5f * b * b;
}

// Exact 1D integral of the hat basis at grid node g over [lo, hi].
__device__ __forceinline__ float bin_w(float lo, float hi, float g) {
    return hat_int(hi - g) - hat_int(lo - g);
}

// NCHW -> NHWC transpose (per n: [C, HW] -> [HW, C]), 32x32 LDS tiles.
// 94 MB HBM traffic @ ~6.3 TB/s -> ~15 us (at ceiling, measured r1).
__global__ __launch_bounds__(256) void transpose_nchw_nhwc(
    const float* __restrict__ src, float* __restrict__ dst, int C, int HW)
{
    __shared__ float tile[32][33];
    const int n = blockIdx.z;
    const int hw0 = blockIdx.x * 32;
    const int c0 = blockIdx.y * 32;
    const float* s = src + (size_t)n * C * HW;
    float* d = dst + (size_t)n * C * HW;
    const int tx = threadIdx.x, ty = threadIdx.y;
    #pragma unroll
    for (int i = ty; i < 32; i += 8) {
        int c = c0 + i, hw = hw0 + tx;
        if (c < C && hw < HW) tile[i][tx] = s[(size_t)c * HW + hw];
    }
    __syncthreads();
    #pragma unroll
    for (int i = ty; i < 32; i += 8) {
        int hw = hw0 + i, c = c0 + tx;
        if (c < C && hw < HW) d[(size_t)hw * C + c] = tile[tx][i];
    }
}

// One block per (roi, c-half): all 7 p-rows fused. 128 threads = 128 channels.
// Per h-row: t[q] = sum_wi wx[q][wi]*f[h][wi][c] (row loaded ONCE for all p),
// then acc[p][q] += wy[p][h]*t[q] only for p with nonzero weight (wave-uniform).
// Output staged via LDS -> fully coalesced float4 stores (no write amplification).
__global__ __launch_bounds__(128) void prroi_pool_fused(
    const float* __restrict__ ft,    // [N, H, W, C]
    const float* __restrict__ rois,  // [R, 5]
    float* __restrict__ out,         // [R, C, PHH, PWW]
    int C, int H, int W)
{
    const int r = blockIdx.x >> 1;
    const int chalf = blockIdx.x & 1;
    const int tid = threadIdx.x;
    const int c = chalf * 128 + tid;

    const float* roi = rois + (size_t)r * 5;
    const int b = (int)roi[0];
    const float x1 = roi[1] * SPATIAL_SCALE;
    const float y1 = roi[2] * SPATIAL_SCALE;
    const float x2 = roi[3] * SPATIAL_SCALE;
    const float y2 = roi[4] * SPATIAL_SCALE;
    const float bw = fmaxf(x2 - x1, 0.0f) / (float)PWW;
    const float bh = fmaxf(y2 - y1, 0.0f) / (float)PHH;
    const float area = bw * bh;
    const float inv_area = (area > 0.0f) ? 1.0f / fmaxf(area, 1e-12f) : 0.0f;

    const int h0 = max(0, (int)ceilf(y1 - 1.0f));
    const int h1 = min(H - 1, (int)floorf(y2 + 1.0f));
    const int w0 = max(0, (int)ceilf(x1 - 1.0f));
    const int w1 = min(W - 1, (int)floorf(x2 + 1.0f));
    const int nh = h1 - h0 + 1;   // <= H
    const int ww = w1 - w0 + 1;   // <= W

    __shared__ float wys[PHH][152];
    __shared__ float wxs[PWW][152];
    __shared__ float obuf[128 * PHH * PWW];  // 24.5 KB staging for coalesced store

    for (int i = tid; i < nh; i += 128) {
        const float g = (float)(h0 + i);
        #pragma unroll
        for (int p = 0; p < PHH; ++p) {
            const float lo = y1 + (float)p * bh;
            wys[p][i] = bin_w(lo, lo + bh, g);
        }
    }
    for (int i = tid; i < ww; i += 128) {
        const float g = (float)(w0 + i);
        #pragma unroll
        for (int q = 0; q < PWW; ++q) {
            const float lo = x1 + (float)q * bw;
            wxs[q][i] = bin_w(lo, lo + bw, g);
        }
    }
    __syncthreads();

    float acc[PHH][PWW];
    #pragma unroll
    for (int p = 0; p < PHH; ++p)
        #pragma unroll
        for (int q = 0; q < PWW; ++q) acc[p][q] = 0.0f;

    for (int i = 0; i < nh; ++i) {
        const float* row = ft + (((size_t)b * H + (h0 + i)) * W + w0) * C + c;
        float t[PWW] = {0.f, 0.f, 0.f, 0.f, 0.f, 0.f, 0.f};
        for (int wi = 0; wi < ww; ++wi) {
            const float f = row[(size_t)wi * C];
            #pragma unroll
            for (int q = 0; q < PWW; ++q)
                t[q] = fmaf(wxs[q][wi], f, t[q]);
        }
        #pragma unroll
        for (int p = 0; p < PHH; ++p) {
            const float wy = wys[p][i];   // LDS broadcast -> wave-uniform branch
            if (wy != 0.0f) {
                #pragma unroll
                for (int q = 0; q < PWW; ++q)
                    acc[p][q] = fmaf(wy, t[q], acc[p][q]);
            }
        }
    }

    // Stage scaled results (stride 49 floats per thread: odd stride, ~conflict-free).
    #pragma unroll
    for (int p = 0; p < PHH; ++p)
        #pragma unroll
        for (int q = 0; q < PWW; ++q)
            obuf[tid * (PHH * PWW) + p * PWW + q] = acc[p][q] * inv_area;
    __syncthreads();

    // Linear float4 copy: block region is 128*49*4 B = 25088 B, contiguous, 16B-aligned.
    float4* o4 = (float4*)(out + ((size_t)r * C + (size_t)chalf * 128) * (PHH * PWW));
    const float4* s4 = (const float4*)obuf;
    #pragma unroll 4
    for (int i = tid; i < 128 * PHH * PWW / 4; i += 128)
        o4[i] = s4[i];
}

// Fallback (no scratch): one thread per output element, reads NCHW directly.
__global__ __launch_bounds__(256) void prroi_pool_nchw(
    const float* __restrict__ f, const float* __restrict__ rois,
    float* __restrict__ out, int C, int H, int W, int R)
{
    const int idx = blockIdx.x * blockDim.x + threadIdx.x;
    const int total = R * C * PHH * PWW;
    if (idx >= total) return;
    const int q = idx % PWW;
    const int p = (idx / PWW) % PHH;
    const int c = (idx / (PWW * PHH)) % C;
    const int r = idx / (PWW * PHH * C);
    const float* roi = rois + (size_t)r * 5;
    const int b = (int)roi[0];
    const float x1 = roi[1] * SPATIAL_SCALE;
    const float y1 = roi[2] * SPATIAL_SCALE;
    const float x2 = roi[3] * SPATIAL_SCALE;
    const float y2 = roi[4] * SPATIAL_SCALE;
    const float bw = fmaxf(x2 - x1, 0.0f) / (float)PWW;
    const float bh = fmaxf(y2 - y1, 0.0f) / (float)PHH;
    const float area = bw * bh;
    const float inv_area = (area > 0.0f) ? 1.0f / fmaxf(area, 1e-12f) : 0.0f;
    const float xlo = x1 + (float)q * bw, xhi = xlo + bw;
    const float ylo = y1 + (float)p * bh, yhi = ylo + bh;
    const int h0 = max(0, (int)ceilf(ylo - 1.0f));
    const int h1 = min(H - 1, (int)floorf(yhi + 1.0f));
    const int w0 = max(0, (int)ceilf(xlo - 1.0f));
    const int w1 = min(W - 1, (int)floorf(xhi + 1.0f));
    float acc = 0.0f;
    for (int h = h0; h <= h1; ++h) {
        const float wy = bin_w(ylo, yhi, (float)h);
        const float* fr = f + (((size_t)b * C + c) * H + h) * W;
        for (int w = w0; w <= w1; ++w)
            acc = fmaf(wy * bin_w(xlo, xhi, (float)w), fr[w], acc);
    }
    out[idx] = acc * inv_area;
}

extern "C" void kernel_launch(void* const* d_in, const int* in_sizes, int n_in,
                              void* d_out, int out_size, void* d_ws, size_t ws_size,
                              hipStream_t stream)
{
    const float* features = (const float*)d_in[0];
    const float* rois = (const float*)d_in[1];
    float* out = (float*)d_out;

    const int C = 256, H = 152, W = 152;
    const int N = in_sizes[0] / (C * H * W);
    const int R = in_sizes[1] / 5;

    const size_t need = (size_t)N * C * H * W * sizeof(float);
    if (ws_size >= need && C == 256) {
        float* ft = (float*)d_ws;
        const int HW = H * W;
        dim3 tgrid((HW + 31) / 32, (C + 31) / 32, N);
        transpose_nchw_nhwc<<<tgrid, dim3(32, 8), 0, stream>>>(features, ft, C, HW);
        prroi_pool_fused<<<R * 2, 128, 0, stream>>>(ft, rois, out, C, H, W);
    } else {
        const int total = R * C * PHH * PWW;
        prroi_pool_nchw<<<(total + 255) / 256, 256, 0, stream>>>(features, rois, out, C, H, W, R);
    }
}

// Round 4
// 92.704 us; speedup vs baseline: 2.3237x; 2.3237x over previous
//
#include <hip/hip_runtime.h>

#define PHH 7
#define PWW 7
static constexpr float SPATIAL_SCALE = 0.0625f;

// Antiderivative of hat function phi(t) = max(0, 1-|t|), saturating to [0,1].
__device__ __forceinline__ float hat_int(float t) {
    t = fminf(fmaxf(t, -1.0f), 1.0f);
    float a = t + 1.0f, b = 1.0f - t;
    return (t <= 0.0f) ? 0.5f * a * a : 1.0f - 0.5f * b * b;
}

// Exact 1D integral of the hat basis at grid node g over [lo, hi].
__device__ __forceinline__ float bin_w(float lo, float hi, float g) {
    return hat_int(hi - g) - hat_int(lo - g);
}

__device__ __forceinline__ unsigned short f32_to_bf16_rne(float x) {
    unsigned int u = __float_as_uint(x);
    unsigned int r = 0x7FFFu + ((u >> 16) & 1u);
    return (unsigned short)((u + r) >> 16);
}

// NCHW f32 -> NHWC bf16 transpose (per n: [C, HW] -> [HW, C]), 32x32 LDS tiles.
// Traffic: 47 MB read + 23.6 MB write ~= 71 MB -> ~12 us at HBM ceiling.
__global__ __launch_bounds__(256) void transpose_nchw_nhwc_bf16(
    const float* __restrict__ src, unsigned short* __restrict__ dst, int C, int HW)
{
    __shared__ float tile[32][33];
    const int n = blockIdx.z;
    const int hw0 = blockIdx.x * 32;
    const int c0 = blockIdx.y * 32;
    const float* s = src + (size_t)n * C * HW;
    unsigned short* d = dst + (size_t)n * C * HW;
    const int tx = threadIdx.x, ty = threadIdx.y;
    #pragma unroll
    for (int i = ty; i < 32; i += 8) {
        int c = c0 + i, hw = hw0 + tx;
        if (c < C && hw < HW) tile[i][tx] = s[(size_t)c * HW + hw];
    }
    __syncthreads();
    #pragma unroll
    for (int i = ty; i < 32; i += 8) {
        int hw = hw0 + i, c = c0 + tx;
        if (c < C && hw < HW) d[(size_t)hw * C + c] = f32_to_bf16_rne(tile[tx][i]);
    }
}

// One block per (roi, c-quarter). lane = channel (64 ch/quarter, coalesced);
// the 4 waves split the window ROWS (i += 4), each wave holds acc[7][7] in
// registers; cross-wave LDS reduce; one contiguous 12.5 KB float4 store.
__global__ __launch_bounds__(256) void prroi_pool_q(
    const unsigned short* __restrict__ ft,  // [N, H, W, 256] bf16
    const float* __restrict__ rois,         // [R, 5]
    float* __restrict__ out,                // [R, 256, PHH, PWW]
    int H, int W)
{
    const int r = blockIdx.x >> 2;
    const int cq = blockIdx.x & 3;
    const int tid = threadIdx.x;
    const int lane = tid & 63;
    const int wig = tid >> 6;
    const int c = cq * 64 + lane;

    const float* roi = rois + (size_t)r * 5;
    const int b = (int)roi[0];
    const float x1 = roi[1] * SPATIAL_SCALE;
    const float y1 = roi[2] * SPATIAL_SCALE;
    const float x2 = roi[3] * SPATIAL_SCALE;
    const float y2 = roi[4] * SPATIAL_SCALE;
    const float bw = fmaxf(x2 - x1, 0.0f) / (float)PWW;
    const float bh = fmaxf(y2 - y1, 0.0f) / (float)PHH;
    const float area = bw * bh;
    const float inv_area = (area > 0.0f) ? 1.0f / fmaxf(area, 1e-12f) : 0.0f;

    const int h0 = max(0, (int)ceilf(y1 - 1.0f));
    const int h1 = min(H - 1, (int)floorf(y2 + 1.0f));
    const int w0 = max(0, (int)ceilf(x1 - 1.0f));
    const int w1 = min(W - 1, (int)floorf(x2 + 1.0f));
    const int nh = h1 - h0 + 1;   // <= H
    const int ww = w1 - w0 + 1;   // <= W

    __shared__ float wys[PHH][152];
    __shared__ float wxs[PWW][152];
    __shared__ float rbuf[64 * PHH * PWW];  // 12.5 KB reduce/staging

    for (int i = tid; i < nh; i += 256) {
        const float g = (float)(h0 + i);
        #pragma unroll
        for (int p = 0; p < PHH; ++p) {
            const float lo = y1 + (float)p * bh;
            wys[p][i] = bin_w(lo, lo + bh, g);
        }
    }
    for (int i = tid; i < ww; i += 256) {
        const float g = (float)(w0 + i);
        #pragma unroll
        for (int q = 0; q < PWW; ++q) {
            const float lo = x1 + (float)q * bw;
            wxs[q][i] = bin_w(lo, lo + bw, g);
        }
    }
    __syncthreads();

    float acc[PHH][PWW];
    #pragma unroll
    for (int p = 0; p < PHH; ++p)
        #pragma unroll
        for (int q = 0; q < PWW; ++q) acc[p][q] = 0.0f;

    // Waves split rows of the window.
    for (int i = wig; i < nh; i += 4) {
        const unsigned short* row =
            ft + (((size_t)b * H + (h0 + i)) * W + w0) * 256 + c;
        float t[PWW] = {0.f, 0.f, 0.f, 0.f, 0.f, 0.f, 0.f};
        for (int wi = 0; wi < ww; ++wi) {
            const float f = __uint_as_float((unsigned int)row[(size_t)wi * 256] << 16);
            #pragma unroll
            for (int q = 0; q < PWW; ++q)
                t[q] = fmaf(wxs[q][wi], f, t[q]);
        }
        #pragma unroll
        for (int p = 0; p < PHH; ++p) {
            const float wy = wys[p][i];   // LDS broadcast -> wave-uniform branch
            if (wy != 0.0f) {
                #pragma unroll
                for (int q = 0; q < PWW; ++q)
                    acc[p][q] = fmaf(wy, t[q], acc[p][q]);
            }
        }
    }

    // Cross-wave reduce into wave 0 (stride 49 floats: odd -> conflict-free).
    for (int g = 1; g < 4; ++g) {
        if (wig == g) {
            #pragma unroll
            for (int p = 0; p < PHH; ++p)
                #pragma unroll
                for (int q = 0; q < PWW; ++q)
                    rbuf[lane * (PHH * PWW) + p * PWW + q] = acc[p][q];
        }
        __syncthreads();
        if (wig == 0) {
            #pragma unroll
            for (int p = 0; p < PHH; ++p)
                #pragma unroll
                for (int q = 0; q < PWW; ++q)
                    acc[p][q] += rbuf[lane * (PHH * PWW) + p * PWW + q];
        }
        __syncthreads();
    }
    if (wig == 0) {
        #pragma unroll
        for (int p = 0; p < PHH; ++p)
            #pragma unroll
            for (int q = 0; q < PWW; ++q)
                rbuf[lane * (PHH * PWW) + p * PWW + q] = acc[p][q] * inv_area;
    }
    __syncthreads();

    // Contiguous coalesced store: 64 ch x 49 = 12544 B, 16B-aligned.
    float4* o4 = (float4*)(out + ((size_t)r * 256 + (size_t)cq * 64) * (PHH * PWW));
    const float4* s4 = (const float4*)rbuf;
    #pragma unroll 4
    for (int i = tid; i < 64 * PHH * PWW / 4; i += 256)
        o4[i] = s4[i];
}

// Fallback (no scratch): one thread per output element, reads NCHW directly.
__global__ __launch_bounds__(256) void prroi_pool_nchw(
    const float* __restrict__ f, const float* __restrict__ rois,
    float* __restrict__ out, int C, int H, int W, int R)
{
    const int idx = blockIdx.x * blockDim.x + threadIdx.x;
    const int total = R * C * PHH * PWW;
    if (idx >= total) return;
    const int q = idx % PWW;
    const int p = (idx / PWW) % PHH;
    const int c = (idx / (PWW * PHH)) % C;
    const int r = idx / (PWW * PHH * C);
    const float* roi = rois + (size_t)r * 5;
    const int b = (int)roi[0];
    const float x1 = roi[1] * SPATIAL_SCALE;
    const float y1 = roi[2] * SPATIAL_SCALE;
    const float x2 = roi[3] * SPATIAL_SCALE;
    const float y2 = roi[4] * SPATIAL_SCALE;
    const float bw = fmaxf(x2 - x1, 0.0f) / (float)PWW;
    const float bh = fmaxf(y2 - y1, 0.0f) / (float)PHH;
    const float area = bw * bh;
    const float inv_area = (area > 0.0f) ? 1.0f / fmaxf(area, 1e-12f) : 0.0f;
    const float xlo = x1 + (float)q * bw, xhi = xlo + bw;
    const float ylo = y1 + (float)p * bh, yhi = ylo + bh;
    const int h0 = max(0, (int)ceilf(ylo - 1.0f));
    const int h1 = min(H - 1, (int)floorf(yhi + 1.0f));
    const int w0 = max(0, (int)ceilf(xlo - 1.0f));
    const int w1 = min(W - 1, (int)floorf(xhi + 1.0f));
    float acc = 0.0f;
    for (int h = h0; h <= h1; ++h) {
        const float wy = bin_w(ylo, yhi, (float)h);
        const float* fr = f + (((size_t)b * C + c) * H + h) * W;
        for (int w = w0; w <= w1; ++w)
            acc = fmaf(wy * bin_w(xlo, xhi, (float)w), fr[w], acc);
    }
    out[idx] = acc * inv_area;
}

extern "C" void kernel_launch(void* const* d_in, const int* in_sizes, int n_in,
                              void* d_out, int out_size, void* d_ws, size_t ws_size,
                              hipStream_t stream)
{
    const float* features = (const float*)d_in[0];
    const float* rois = (const float*)d_in[1];
    float* out = (float*)d_out;

    const int C = 256, H = 152, W = 152;
    const int N = in_sizes[0] / (C * H * W);
    const int R = in_sizes[1] / 5;

    const size_t need = (size_t)N * C * H * W * sizeof(unsigned short);
    if (ws_size >= need && C == 256) {
        unsigned short* ft = (unsigned short*)d_ws;
        const int HW = H * W;
        dim3 tgrid((HW + 31) / 32, (C + 31) / 32, N);
        transpose_nchw_nhwc_bf16<<<tgrid, dim3(32, 8), 0, stream>>>(features, ft, C, HW);
        prroi_pool_q<<<R * 4, 256, 0, stream>>>(ft, rois, out, H, W);
    } else {
        const int total = R * C * PHH * PWW;
        prroi_pool_nchw<<<(total + 255) / 256, 256, 0, stream>>>(features, rois, out, C, H, W, R);
    }
}

// Round 5
// 71.413 us; speedup vs baseline: 3.0164x; 1.2981x over previous
//
#include <hip/hip_runtime.h>

#define PHH 7
#define PWW 7
static constexpr float SPATIAL_SCALE = 0.0625f;

// Antiderivative of hat function phi(t) = max(0, 1-|t|), saturating to [0,1].
__device__ __forceinline__ float hat_int(float t) {
    t = fminf(fmaxf(t, -1.0f), 1.0f);
    float a = t + 1.0f, b = 1.0f - t;
    return (t <= 0.0f) ? 0.5f * a * a : 1.0f - 0.5f * b * b;
}

// Exact 1D integral of the hat basis at grid node g over [lo, hi].
__device__ __forceinline__ float bin_w(float lo, float hi, float g) {
    return hat_int(hi - g) - hat_int(lo - g);
}

__device__ __forceinline__ unsigned short f32_to_bf16_rne(float x) {
    unsigned int u = __float_as_uint(x);
    unsigned int r = 0x7FFFu + ((u >> 16) & 1u);
    return (unsigned short)((u + r) >> 16);
}

// NCHW f32 -> NHWC bf16 transpose (per n: [C, HW] -> [HW, C]), 32x32 LDS tiles.
// 47 MB read + 23.6 MB write ~= 71 MB -> ~12 us at HBM ceiling (measured r4).
__global__ __launch_bounds__(256) void transpose_nchw_nhwc_bf16(
    const float* __restrict__ src, unsigned short* __restrict__ dst, int C, int HW)
{
    __shared__ float tile[32][33];
    const int n = blockIdx.z;
    const int hw0 = blockIdx.x * 32;
    const int c0 = blockIdx.y * 32;
    const float* s = src + (size_t)n * C * HW;
    unsigned short* d = dst + (size_t)n * C * HW;
    const int tx = threadIdx.x, ty = threadIdx.y;
    #pragma unroll
    for (int i = ty; i < 32; i += 8) {
        int c = c0 + i, hw = hw0 + tx;
        if (c < C && hw < HW) tile[i][tx] = s[(size_t)c * HW + hw];
    }
    __syncthreads();
    #pragma unroll
    for (int i = ty; i < 32; i += 8) {
        int hw = hw0 + i, c = c0 + tx;
        if (c < C && hw < HW) d[(size_t)hw * C + c] = f32_to_bf16_rne(tile[tx][i]);
    }
}

// One block per (roi, p-bin): 3584 fine-grained blocks for load balance.
// 128 threads = 2 waves; wave owns 128 channels (lane -> ushort2 = 2 channels,
// fully coalesced 256 B/wave loads); no cross-wave reduction needed.
// y-contraction FIRST: u[wi] = sum_h wy[h]*f[h][wi]  (1 cvt + 1 FMA per elem),
// then acc[q] += sum_wi wx[q][wi]*u[wi]  (7 FMA per column, wx via ds_read_b128).
__global__ __launch_bounds__(128) void prroi_pool_p(
    const unsigned short* __restrict__ ft,  // [N, H, W, 256] bf16
    const float* __restrict__ rois,         // [R, 5]
    float* __restrict__ out,                // [R, 256, PHH, PWW]
    int H, int W)
{
    const int r = blockIdx.x / PHH;
    const int p = blockIdx.x % PHH;
    const int tid = threadIdx.x;
    const int wave = tid >> 6;
    const int lane = tid & 63;
    const int c = wave * 128 + lane * 2;

    const float* roi = rois + (size_t)r * 5;
    const int b = (int)roi[0];
    const float x1 = roi[1] * SPATIAL_SCALE;
    const float y1 = roi[2] * SPATIAL_SCALE;
    const float x2 = roi[3] * SPATIAL_SCALE;
    const float y2 = roi[4] * SPATIAL_SCALE;
    const float bw = fmaxf(x2 - x1, 0.0f) / (float)PWW;
    const float bh = fmaxf(y2 - y1, 0.0f) / (float)PHH;
    const float area = bw * bh;
    const float inv_area = (area > 0.0f) ? 1.0f / fmaxf(area, 1e-12f) : 0.0f;

    const float ylo = y1 + (float)p * bh;
    const float yhi = ylo + bh;
    const int h0 = max(0, (int)ceilf(ylo - 1.0f));
    const int h1 = min(H - 1, (int)floorf(yhi + 1.0f));
    const int w0 = max(0, (int)ceilf(x1 - 1.0f));
    const int w1 = min(W - 1, (int)floorf(x2 + 1.0f));
    const int nh = min(h1 - h0 + 1, 16);  // p-bin spans <= bh+2 ~ 9 rows here
    const int ww = w1 - w0 + 1;           // <= W (152)
    const int wwpad = (ww + 7) & ~7;      // chunk-of-8 padded

    __shared__ float wx8[152 * 8];  // [wi][q] padded to 8 (q=7 slot = 0): b128-readable
    __shared__ float wys[16];

    for (int i = tid; i < wwpad; i += 128) {
        const float g = (float)(w0 + i);
        #pragma unroll
        for (int q = 0; q < PWW; ++q) {
            const float lo = x1 + (float)q * bw;
            wx8[i * 8 + q] = (i < ww) ? bin_w(lo, lo + bw, g) : 0.0f;
        }
        wx8[i * 8 + 7] = 0.0f;
    }
    for (int i = tid; i < nh; i += 128)
        wys[i] = bin_w(ylo, yhi, (float)(h0 + i));
    __syncthreads();

    float acc0[PWW] = {0.f, 0.f, 0.f, 0.f, 0.f, 0.f, 0.f};
    float acc1[PWW] = {0.f, 0.f, 0.f, 0.f, 0.f, 0.f, 0.f};

    const size_t rowstride = (size_t)W * 256;  // in u16 elements
    const unsigned short* base =
        ft + ((size_t)b * H + (size_t)max(h0, 0)) * rowstride + (size_t)w0 * 256 + c;

    for (int chunk = 0; chunk < ww; chunk += 8) {
        // Column offsets, clamped so padded lanes read a valid (weight-0) address.
        int off[8];
        #pragma unroll
        for (int j = 0; j < 8; ++j)
            off[j] = (chunk + j < ww) ? (chunk + j) * 256 : 0;

        float u0[8] = {0.f, 0.f, 0.f, 0.f, 0.f, 0.f, 0.f, 0.f};
        float u1[8] = {0.f, 0.f, 0.f, 0.f, 0.f, 0.f, 0.f, 0.f};
        for (int i = 0; i < nh; ++i) {
            const float wy = wys[i];
            const unsigned short* rp = base + (size_t)i * rowstride;
            #pragma unroll
            for (int j = 0; j < 8; ++j) {
                const unsigned int v = *(const unsigned int*)(rp + off[j]);
                const float f0 = __uint_as_float(v << 16);
                const float f1 = __uint_as_float(v & 0xFFFF0000u);
                u0[j] = fmaf(wy, f0, u0[j]);
                u1[j] = fmaf(wy, f1, u1[j]);
            }
        }
        #pragma unroll
        for (int j = 0; j < 8; ++j) {
            const float4 wa = *(const float4*)&wx8[(chunk + j) * 8];
            const float4 wb = *(const float4*)&wx8[(chunk + j) * 8 + 4];
            acc0[0] = fmaf(wa.x, u0[j], acc0[0]); acc1[0] = fmaf(wa.x, u1[j], acc1[0]);
            acc0[1] = fmaf(wa.y, u0[j], acc0[1]); acc1[1] = fmaf(wa.y, u1[j], acc1[1]);
            acc0[2] = fmaf(wa.z, u0[j], acc0[2]); acc1[2] = fmaf(wa.z, u1[j], acc1[2]);
            acc0[3] = fmaf(wa.w, u0[j], acc0[3]); acc1[3] = fmaf(wa.w, u1[j], acc1[3]);
            acc0[4] = fmaf(wb.x, u0[j], acc0[4]); acc1[4] = fmaf(wb.x, u1[j], acc1[4]);
            acc0[5] = fmaf(wb.y, u0[j], acc0[5]); acc1[5] = fmaf(wb.y, u1[j], acc1[5]);
            acc0[6] = fmaf(wb.z, u0[j], acc0[6]); acc1[6] = fmaf(wb.z, u1[j], acc1[6]);
        }
    }

    float* o = out + ((size_t)r * 256 + c) * (PHH * PWW) + p * PWW;
    #pragma unroll
    for (int q = 0; q < PWW; ++q) o[q] = acc0[q] * inv_area;
    #pragma unroll
    for (int q = 0; q < PWW; ++q) o[PHH * PWW + q] = acc1[q] * inv_area;
}

// Fallback (no scratch): one thread per output element, reads NCHW directly.
__global__ __launch_bounds__(256) void prroi_pool_nchw(
    const float* __restrict__ f, const float* __restrict__ rois,
    float* __restrict__ out, int C, int H, int W, int R)
{
    const int idx = blockIdx.x * blockDim.x + threadIdx.x;
    const int total = R * C * PHH * PWW;
    if (idx >= total) return;
    const int q = idx % PWW;
    const int p = (idx / PWW) % PHH;
    const int c = (idx / (PWW * PHH)) % C;
    const int r = idx / (PWW * PHH * C);
    const float* roi = rois + (size_t)r * 5;
    const int b = (int)roi[0];
    const float x1 = roi[1] * SPATIAL_SCALE;
    const float y1 = roi[2] * SPATIAL_SCALE;
    const float x2 = roi[3] * SPATIAL_SCALE;
    const float y2 = roi[4] * SPATIAL_SCALE;
    const float bw = fmaxf(x2 - x1, 0.0f) / (float)PWW;
    const float bh = fmaxf(y2 - y1, 0.0f) / (float)PHH;
    const float area = bw * bh;
    const float inv_area = (area > 0.0f) ? 1.0f / fmaxf(area, 1e-12f) : 0.0f;
    const float xlo = x1 + (float)q * bw, xhi = xlo + bw;
    const float ylo = y1 + (float)p * bh, yhi = ylo + bh;
    const int h0 = max(0, (int)ceilf(ylo - 1.0f));
    const int h1 = min(H - 1, (int)floorf(yhi + 1.0f));
    const int w0 = max(0, (int)ceilf(xlo - 1.0f));
    const int w1 = min(W - 1, (int)floorf(xhi + 1.0f));
    float acc = 0.0f;
    for (int h = h0; h <= h1; ++h) {
        const float wy = bin_w(ylo, yhi, (float)h);
        const float* fr = f + (((size_t)b * C + c) * H + h) * W;
        for (int w = w0; w <= w1; ++w)
            acc = fmaf(wy * bin_w(xlo, xhi, (float)w), fr[w], acc);
    }
    out[idx] = acc * inv_area;
}

extern "C" void kernel_launch(void* const* d_in, const int* in_sizes, int n_in,
                              void* d_out, int out_size, void* d_ws, size_t ws_size,
                              hipStream_t stream)
{
    const float* features = (const float*)d_in[0];
    const float* rois = (const float*)d_in[1];
    float* out = (float*)d_out;

    const int C = 256, H = 152, W = 152;
    const int N = in_sizes[0] / (C * H * W);
    const int R = in_sizes[1] / 5;

    const size_t need = (size_t)N * C * H * W * sizeof(unsigned short);
    if (ws_size >= need && C == 256) {
        unsigned short* ft = (unsigned short*)d_ws;
        const int HW = H * W;
        dim3 tgrid((HW + 31) / 32, (C + 31) / 32, N);
        transpose_nchw_nhwc_bf16<<<tgrid, dim3(32, 8), 0, stream>>>(features, ft, C, HW);
        prroi_pool_p<<<R * PHH, 128, 0, stream>>>(ft, rois, out, H, W);
    } else {
        const int total = R * C * PHH * PWW;
        prroi_pool_nchw<<<(total + 255) / 256, 256, 0, stream>>>(features, rois, out, C, H, W, R);
    }
}

// Round 6
// 69.790 us; speedup vs baseline: 3.0866x; 1.0233x over previous
//
#include <hip/hip_runtime.h>

#define PHH 7
#define PWW 7
static constexpr float SPATIAL_SCALE = 0.0625f;

// Antiderivative of hat function phi(t) = max(0, 1-|t|), saturating to [0,1].
__device__ __forceinline__ float hat_int(float t) {
    t = fminf(fmaxf(t, -1.0f), 1.0f);
    float a = t + 1.0f, b = 1.0f - t;
    return (t <= 0.0f) ? 0.5f * a * a : 1.0f - 0.5f * b * b;
}

// Exact 1D integral of the hat basis at grid node g over [lo, hi].
__device__ __forceinline__ float bin_w(float lo, float hi, float g) {
    return hat_int(hi - g) - hat_int(lo - g);
}

__device__ __forceinline__ unsigned short f32_to_bf16_rne(float x) {
    unsigned int u = __float_as_uint(x);
    unsigned int r = 0x7FFFu + ((u >> 16) & 1u);
    return (unsigned short)((u + r) >> 16);
}

__device__ __forceinline__ float bf_lo(unsigned int v) {
    return __uint_as_float(v << 16);
}
__device__ __forceinline__ float bf_hi(unsigned int v) {
    return __uint_as_float(v & 0xFFFF0000u);
}

// NCHW f32 -> NHWC bf16 transpose (per n: [C, HW] -> [HW, C]), 32x32 LDS tiles.
// 47 MB read + 23.6 MB write ~= 71 MB -> ~12 us at HBM ceiling (measured r4/r5).
__global__ __launch_bounds__(256) void transpose_nchw_nhwc_bf16(
    const float* __restrict__ src, unsigned short* __restrict__ dst, int C, int HW)
{
    __shared__ float tile[32][33];
    const int n = blockIdx.z;
    const int hw0 = blockIdx.x * 32;
    const int c0 = blockIdx.y * 32;
    const float* s = src + (size_t)n * C * HW;
    unsigned short* d = dst + (size_t)n * C * HW;
    const int tx = threadIdx.x, ty = threadIdx.y;
    #pragma unroll
    for (int i = ty; i < 32; i += 8) {
        int c = c0 + i, hw = hw0 + tx;
        if (c < C && hw < HW) tile[i][tx] = s[(size_t)c * HW + hw];
    }
    __syncthreads();
    #pragma unroll
    for (int i = ty; i < 32; i += 8) {
        int hw = hw0 + i, c = c0 + tx;
        if (c < C && hw < HW) d[(size_t)hw * C + c] = f32_to_bf16_rne(tile[tx][i]);
    }
}

// One block per (roi, p-bin), XCD-swizzled so each roi's 7 p-blocks share an
// XCD (L2 window/halo reuse). 256 threads = 4 waves; lane = 4 channels
// (uint2 = 4 bf16, one wave covers all 256 ch of a column); waves split window
// ROWS (i = wig, step 4, unroll x2 -> 16 loads in flight). y-contraction first:
// u[ch][j] = sum_h wy*f, then acc[q][ch] += wx[q][j]*u[ch][j] once per column.
// Cross-wave LDS reduce (stride 29: odd -> conflict-free).
__global__ __launch_bounds__(256) void prroi_pool_p4(
    const unsigned short* __restrict__ ft,  // [N, H, W, 256] bf16
    const float* __restrict__ rois,         // [R, 5]
    float* __restrict__ out,                // [R, 256, PHH, PWW]
    int H, int W, int R)
{
    // Bijective XCD swizzle: hardware sends consecutive blockIdx round-robin
    // to the 8 XCDs. Remap so XCD k owns a contiguous task chunk (448 = 7*64
    // tasks = 64 whole rois when R = 512).
    const int nwg = R * PHH;
    int task = (int)blockIdx.x;
    if ((nwg & 7) == 0) {
        const int chunk = nwg >> 3;
        task = (task & 7) * chunk + (task >> 3);
    }
    const int r = task / PHH;
    const int p = task % PHH;

    const int tid = threadIdx.x;
    const int wig = tid >> 6;
    const int lane = tid & 63;
    const int c = lane * 4;

    const float* roi = rois + (size_t)r * 5;
    const int b = (int)roi[0];
    const float x1 = roi[1] * SPATIAL_SCALE;
    const float y1 = roi[2] * SPATIAL_SCALE;
    const float x2 = roi[3] * SPATIAL_SCALE;
    const float y2 = roi[4] * SPATIAL_SCALE;
    const float bw = fmaxf(x2 - x1, 0.0f) / (float)PWW;
    const float bh = fmaxf(y2 - y1, 0.0f) / (float)PHH;
    const float area = bw * bh;
    const float inv_area = (area > 0.0f) ? 1.0f / fmaxf(area, 1e-12f) : 0.0f;

    const float ylo = y1 + (float)p * bh;
    const float yhi = ylo + bh;
    const int h0 = max(0, (int)ceilf(ylo - 1.0f));
    const int h1 = min(H - 1, (int)floorf(yhi + 1.0f));
    const int w0 = max(0, (int)ceilf(x1 - 1.0f));
    const int w1 = min(W - 1, (int)floorf(x2 + 1.0f));
    const int nh = min(h1 - h0 + 1, 16);  // p-bin spans <= bh+3 ~ 10 rows
    const int ww = w1 - w0 + 1;           // <= W (152)

    __shared__ float wx8[152 * 8];   // [wi][q], q padded to 8 (slot 7 = 0)
    __shared__ float wys[16];
    __shared__ float rbuf[64 * 29];  // stride 29 (odd): conflict-free reduce

    const int wwpad = (ww + 7) & ~7;
    for (int i = tid; i < wwpad; i += 256) {
        const float g = (float)(w0 + i);
        #pragma unroll
        for (int q = 0; q < PWW; ++q) {
            const float lo = x1 + (float)q * bw;
            wx8[i * 8 + q] = (i < ww) ? bin_w(lo, lo + bw, g) : 0.0f;
        }
        wx8[i * 8 + 7] = 0.0f;
    }
    for (int i = tid; i < nh; i += 256)
        wys[i] = bin_w(ylo, yhi, (float)(h0 + i));
    __syncthreads();

    float acc[PWW][4];
    #pragma unroll
    for (int q = 0; q < PWW; ++q)
        #pragma unroll
        for (int ch = 0; ch < 4; ++ch) acc[q][ch] = 0.0f;

    const size_t rowstride = (size_t)W * 256;  // u16 elements
    const unsigned short* base =
        ft + ((size_t)b * H + (size_t)h0) * rowstride + (size_t)w0 * 256 + c;

    for (int chunk = 0; chunk < ww; chunk += 8) {
        int off[8];
        #pragma unroll
        for (int j = 0; j < 8; ++j)
            off[j] = (chunk + j < ww) ? (chunk + j) * 256 : 0;

        float u[4][8];
        #pragma unroll
        for (int ch = 0; ch < 4; ++ch)
            #pragma unroll
            for (int j = 0; j < 8; ++j) u[ch][j] = 0.0f;

        int i = wig;
        // Two of this wave's rows in flight (16 x 8B loads).
        for (; i + 4 < nh; i += 8) {
            const unsigned short* rp0 = base + (size_t)i * rowstride;
            const unsigned short* rp1 = base + (size_t)(i + 4) * rowstride;
            uint2 v0[8], v1[8];
            #pragma unroll
            for (int j = 0; j < 8; ++j) v0[j] = *(const uint2*)(rp0 + off[j]);
            #pragma unroll
            for (int j = 0; j < 8; ++j) v1[j] = *(const uint2*)(rp1 + off[j]);
            const float wy0 = wys[i];
            const float wy1 = wys[i + 4];
            #pragma unroll
            for (int j = 0; j < 8; ++j) {
                u[0][j] = fmaf(wy0, bf_lo(v0[j].x), u[0][j]);
                u[1][j] = fmaf(wy0, bf_hi(v0[j].x), u[1][j]);
                u[2][j] = fmaf(wy0, bf_lo(v0[j].y), u[2][j]);
                u[3][j] = fmaf(wy0, bf_hi(v0[j].y), u[3][j]);
            }
            #pragma unroll
            for (int j = 0; j < 8; ++j) {
                u[0][j] = fmaf(wy1, bf_lo(v1[j].x), u[0][j]);
                u[1][j] = fmaf(wy1, bf_hi(v1[j].x), u[1][j]);
                u[2][j] = fmaf(wy1, bf_lo(v1[j].y), u[2][j]);
                u[3][j] = fmaf(wy1, bf_hi(v1[j].y), u[3][j]);
            }
        }
        for (; i < nh; i += 4) {
            const unsigned short* rp0 = base + (size_t)i * rowstride;
            uint2 v0[8];
            #pragma unroll
            for (int j = 0; j < 8; ++j) v0[j] = *(const uint2*)(rp0 + off[j]);
            const float wy0 = wys[i];
            #pragma unroll
            for (int j = 0; j < 8; ++j) {
                u[0][j] = fmaf(wy0, bf_lo(v0[j].x), u[0][j]);
                u[1][j] = fmaf(wy0, bf_hi(v0[j].x), u[1][j]);
                u[2][j] = fmaf(wy0, bf_lo(v0[j].y), u[2][j]);
                u[3][j] = fmaf(wy0, bf_hi(v0[j].y), u[3][j]);
            }
        }

        #pragma unroll
        for (int j = 0; j < 8; ++j) {
            const float4 wa = *(const float4*)&wx8[(chunk + j) * 8];
            const float4 wb = *(const float4*)&wx8[(chunk + j) * 8 + 4];
            #pragma unroll
            for (int ch = 0; ch < 4; ++ch) {
                acc[0][ch] = fmaf(wa.x, u[ch][j], acc[0][ch]);
                acc[1][ch] = fmaf(wa.y, u[ch][j], acc[1][ch]);
                acc[2][ch] = fmaf(wa.z, u[ch][j], acc[2][ch]);
                acc[3][ch] = fmaf(wa.w, u[ch][j], acc[3][ch]);
                acc[4][ch] = fmaf(wb.x, u[ch][j], acc[4][ch]);
                acc[5][ch] = fmaf(wb.y, u[ch][j], acc[5][ch]);
                acc[6][ch] = fmaf(wb.z, u[ch][j], acc[6][ch]);
            }
        }
    }

    // 4-way cross-wave reduce into wave 0 (sequential, 7.4 KB buffer).
    for (int g = 1; g < 4; ++g) {
        if (wig == g) {
            #pragma unroll
            for (int q = 0; q < PWW; ++q)
                #pragma unroll
                for (int ch = 0; ch < 4; ++ch)
                    rbuf[lane * 29 + q * 4 + ch] = acc[q][ch];
        }
        __syncthreads();
        if (wig == 0) {
            #pragma unroll
            for (int q = 0; q < PWW; ++q)
                #pragma unroll
                for (int ch = 0; ch < 4; ++ch)
                    acc[q][ch] += rbuf[lane * 29 + q * 4 + ch];
        }
        __syncthreads();
    }

    if (wig == 0) {
        float* o = out + ((size_t)r * 256 + c) * (PHH * PWW) + p * PWW;
        #pragma unroll
        for (int ch = 0; ch < 4; ++ch)
            #pragma unroll
            for (int q = 0; q < PWW; ++q)
                o[(size_t)ch * (PHH * PWW) + q] = acc[q][ch] * inv_area;
    }
}

// Fallback (no scratch): one thread per output element, reads NCHW directly.
__global__ __launch_bounds__(256) void prroi_pool_nchw(
    const float* __restrict__ f, const float* __restrict__ rois,
    float* __restrict__ out, int C, int H, int W, int R)
{
    const int idx = blockIdx.x * blockDim.x + threadIdx.x;
    const int total = R * C * PHH * PWW;
    if (idx >= total) return;
    const int q = idx % PWW;
    const int p = (idx / PWW) % PHH;
    const int c = (idx / (PWW * PHH)) % C;
    const int r = idx / (PWW * PHH * C);
    const float* roi = rois + (size_t)r * 5;
    const int b = (int)roi[0];
    const float x1 = roi[1] * SPATIAL_SCALE;
    const float y1 = roi[2] * SPATIAL_SCALE;
    const float x2 = roi[3] * SPATIAL_SCALE;
    const float y2 = roi[4] * SPATIAL_SCALE;
    const float bw = fmaxf(x2 - x1, 0.0f) / (float)PWW;
    const float bh = fmaxf(y2 - y1, 0.0f) / (float)PHH;
    const float area = bw * bh;
    const float inv_area = (area > 0.0f) ? 1.0f / fmaxf(area, 1e-12f) : 0.0f;
    const float xlo = x1 + (float)q * bw, xhi = xlo + bw;
    const float ylo = y1 + (float)p * bh, yhi = ylo + bh;
    const int h0 = max(0, (int)ceilf(ylo - 1.0f));
    const int h1 = min(H - 1, (int)floorf(yhi + 1.0f));
    const int w0 = max(0, (int)ceilf(xlo - 1.0f));
    const int w1 = min(W - 1, (int)floorf(xhi + 1.0f));
    float acc = 0.0f;
    for (int h = h0; h <= h1; ++h) {
        const float wy = bin_w(ylo, yhi, (float)h);
        const float* fr = f + (((size_t)b * C + c) * H + h) * W;
        for (int w = w0; w <= w1; ++w)
            acc = fmaf(wy * bin_w(xlo, xhi, (float)w), fr[w], acc);
    }
    out[idx] = acc * inv_area;
}

extern "C" void kernel_launch(void* const* d_in, const int* in_sizes, int n_in,
                              void* d_out, int out_size, void* d_ws, size_t ws_size,
                              hipStream_t stream)
{
    const float* features = (const float*)d_in[0];
    const float* rois = (const float*)d_in[1];
    float* out = (float*)d_out;

    const int C = 256, H = 152, W = 152;
    const int N = in_sizes[0] / (C * H * W);
    const int R = in_sizes[1] / 5;

    const size_t need = (size_t)N * C * H * W * sizeof(unsigned short);
    if (ws_size >= need && C == 256) {
        unsigned short* ft = (unsigned short*)d_ws;
        const int HW = H * W;
        dim3 tgrid((HW + 31) / 32, (C + 31) / 32, N);
        transpose_nchw_nhwc_bf16<<<tgrid, dim3(32, 8), 0, stream>>>(features, ft, C, HW);
        prroi_pool_p4<<<R * PHH, 256, 0, stream>>>(ft, rois, out, H, W, R);
    } else {
        const int total = R * C * PHH * PWW;
        prroi_pool_nchw<<<(total + 255) / 256, 256, 0, stream>>>(features, rois, out, C, H, W, R);
    }
}

// Round 7
// 60.063 us; speedup vs baseline: 3.5865x; 1.1620x over previous
//
#include <hip/hip_runtime.h>

#define PHH 7
#define PWW 7
static constexpr float SPATIAL_SCALE = 0.0625f;

// Antiderivative of hat function phi(t) = max(0, 1-|t|), saturating to [0,1].
__device__ __forceinline__ float hat_int(float t) {
    t = fminf(fmaxf(t, -1.0f), 1.0f);
    float a = t + 1.0f, b = 1.0f - t;
    return (t <= 0.0f) ? 0.5f * a * a : 1.0f - 0.5f * b * b;
}

// Exact 1D integral of the hat basis at grid node g over [lo, hi].
__device__ __forceinline__ float bin_w(float lo, float hi, float g) {
    return hat_int(hi - g) - hat_int(lo - g);
}

__device__ __forceinline__ unsigned short f32_to_bf16_rne(float x) {
    unsigned int u = __float_as_uint(x);
    unsigned int r = 0x7FFFu + ((u >> 16) & 1u);
    return (unsigned short)((u + r) >> 16);
}

__device__ __forceinline__ float bf_lo(unsigned int v) {
    return __uint_as_float(v << 16);
}
__device__ __forceinline__ float bf_hi(unsigned int v) {
    return __uint_as_float(v & 0xFFFF0000u);
}

// NCHW f32 -> NHWC bf16 transpose (per n: [C, HW] -> [HW, C]), 32x32 LDS tiles.
// 47 MB read + 23.6 MB write ~= 71 MB -> ~12 us at HBM ceiling (measured r4/r5).
__global__ __launch_bounds__(256) void transpose_nchw_nhwc_bf16(
    const float* __restrict__ src, unsigned short* __restrict__ dst, int C, int HW)
{
    __shared__ float tile[32][33];
    const int n = blockIdx.z;
    const int hw0 = blockIdx.x * 32;
    const int c0 = blockIdx.y * 32;
    const float* s = src + (size_t)n * C * HW;
    unsigned short* d = dst + (size_t)n * C * HW;
    const int tx = threadIdx.x, ty = threadIdx.y;
    #pragma unroll
    for (int i = ty; i < 32; i += 8) {
        int c = c0 + i, hw = hw0 + tx;
        if (c < C && hw < HW) tile[i][tx] = s[(size_t)c * HW + hw];
    }
    __syncthreads();
    #pragma unroll
    for (int i = ty; i < 32; i += 8) {
        int hw = hw0 + i, c = c0 + tx;
        if (c < C && hw < HW) d[(size_t)hw * C + c] = f32_to_bf16_rne(tile[tx][i]);
    }
}

// One block per (roi, p-bin), XCD-swizzled (roi's 7 p-blocks share an XCD's L2).
// 4 waves split column CHUNKS (8 cols x all nh rows each): each wave computes
// the complete y-contraction u[ch][8] for its chunk and applies wx ONCE
// (no redundant x-contraction, halving critical-path VALU vs row-split).
// Lane = 4 channels (uint2 = 4 bf16; wave covers all 256 ch, coalesced 512B).
// Single-barrier 4-partial reduce (stride-29 LDS) + 256-thread coop store.
__global__ __launch_bounds__(256) void prroi_pool_cs(
    const unsigned short* __restrict__ ft,  // [N, H, W, 256] bf16
    const float* __restrict__ rois,         // [R, 5]
    float* __restrict__ out,                // [R, 256, PHH, PWW]
    int H, int W, int R)
{
    // Bijective XCD swizzle: consecutive blockIdx round-robin over 8 XCDs;
    // remap so each XCD owns a contiguous task chunk (whole rois).
    const int nwg = R * PHH;
    int task = (int)blockIdx.x;
    if ((nwg & 7) == 0) {
        const int cpx = nwg >> 3;
        task = (task & 7) * cpx + (task >> 3);
    }
    const int r = task / PHH;
    const int p = task % PHH;

    const int tid = threadIdx.x;
    const int wig = tid >> 6;
    const int lane = tid & 63;
    const int c0 = lane * 4;

    const float* roi = rois + (size_t)r * 5;
    const int b = (int)roi[0];
    const float x1 = roi[1] * SPATIAL_SCALE;
    const float y1 = roi[2] * SPATIAL_SCALE;
    const float x2 = roi[3] * SPATIAL_SCALE;
    const float y2 = roi[4] * SPATIAL_SCALE;
    const float bw = fmaxf(x2 - x1, 0.0f) / (float)PWW;
    const float bh = fmaxf(y2 - y1, 0.0f) / (float)PHH;
    const float area = bw * bh;
    const float inv_area = (area > 0.0f) ? 1.0f / fmaxf(area, 1e-12f) : 0.0f;

    const float ylo = y1 + (float)p * bh;
    const float yhi = ylo + bh;
    const int h0 = max(0, (int)ceilf(ylo - 1.0f));
    const int h1 = min(H - 1, (int)floorf(yhi + 1.0f));
    const int w0 = max(0, (int)ceilf(x1 - 1.0f));
    const int w1 = min(W - 1, (int)floorf(x2 + 1.0f));
    const int nh = min(h1 - h0 + 1, 16);  // p-bin spans <= bh+3 ~ 10 rows
    const int ww = w1 - w0 + 1;           // <= W (152)
    const int wwpad = (ww + 7) & ~7;

    __shared__ float wx8[152 * 8];        // [wi][q], q padded to 8 (slot 7 = 0)
    __shared__ float wys[16];
    __shared__ float rbuf[4 * 64 * 29];   // stride 29 (odd) -> conflict-free

    for (int i = tid; i < wwpad; i += 256) {
        const float g = (float)(w0 + i);
        #pragma unroll
        for (int q = 0; q < PWW; ++q) {
            const float lo = x1 + (float)q * bw;
            wx8[i * 8 + q] = (i < ww) ? bin_w(lo, lo + bw, g) : 0.0f;
        }
        wx8[i * 8 + 7] = 0.0f;
    }
    for (int i = tid; i < nh; i += 256)
        wys[i] = bin_w(ylo, yhi, (float)(h0 + i));
    __syncthreads();

    float acc[PWW][4];
    #pragma unroll
    for (int q = 0; q < PWW; ++q)
        #pragma unroll
        for (int ch = 0; ch < 4; ++ch) acc[q][ch] = 0.0f;

    const size_t rowstride = (size_t)W * 256;  // u16 elements
    const unsigned short* base =
        ft + ((size_t)b * H + (size_t)h0) * rowstride + (size_t)w0 * 256 + c0;

    // Each wave owns column chunks wig, wig+4, wig+8, ... (8 cols each).
    for (int chunk = wig * 8; chunk < ww; chunk += 32) {
        int off[8];
        #pragma unroll
        for (int j = 0; j < 8; ++j)
            off[j] = (chunk + j < ww) ? (chunk + j) * 256 : 0;

        float u[4][8];
        #pragma unroll
        for (int ch = 0; ch < 4; ++ch)
            #pragma unroll
            for (int j = 0; j < 8; ++j) u[ch][j] = 0.0f;

        int i = 0;
        for (; i + 1 < nh; i += 2) {   // 16 x 8B loads in flight
            const unsigned short* rp0 = base + (size_t)i * rowstride;
            const unsigned short* rp1 = rp0 + rowstride;
            uint2 v0[8], v1[8];
            #pragma unroll
            for (int j = 0; j < 8; ++j) v0[j] = *(const uint2*)(rp0 + off[j]);
            #pragma unroll
            for (int j = 0; j < 8; ++j) v1[j] = *(const uint2*)(rp1 + off[j]);
            const float wy0 = wys[i];
            const float wy1 = wys[i + 1];
            #pragma unroll
            for (int j = 0; j < 8; ++j) {
                u[0][j] = fmaf(wy0, bf_lo(v0[j].x), u[0][j]);
                u[1][j] = fmaf(wy0, bf_hi(v0[j].x), u[1][j]);
                u[2][j] = fmaf(wy0, bf_lo(v0[j].y), u[2][j]);
                u[3][j] = fmaf(wy0, bf_hi(v0[j].y), u[3][j]);
            }
            #pragma unroll
            for (int j = 0; j < 8; ++j) {
                u[0][j] = fmaf(wy1, bf_lo(v1[j].x), u[0][j]);
                u[1][j] = fmaf(wy1, bf_hi(v1[j].x), u[1][j]);
                u[2][j] = fmaf(wy1, bf_lo(v1[j].y), u[2][j]);
                u[3][j] = fmaf(wy1, bf_hi(v1[j].y), u[3][j]);
            }
        }
        if (i < nh) {
            const unsigned short* rp0 = base + (size_t)i * rowstride;
            uint2 v0[8];
            #pragma unroll
            for (int j = 0; j < 8; ++j) v0[j] = *(const uint2*)(rp0 + off[j]);
            const float wy0 = wys[i];
            #pragma unroll
            for (int j = 0; j < 8; ++j) {
                u[0][j] = fmaf(wy0, bf_lo(v0[j].x), u[0][j]);
                u[1][j] = fmaf(wy0, bf_hi(v0[j].x), u[1][j]);
                u[2][j] = fmaf(wy0, bf_lo(v0[j].y), u[2][j]);
                u[3][j] = fmaf(wy0, bf_hi(v0[j].y), u[3][j]);
            }
        }

        // Apply wx ONCE per column (this wave owns the column completely).
        #pragma unroll
        for (int j = 0; j < 8; ++j) {
            const float4 wa = *(const float4*)&wx8[(chunk + j) * 8];
            const float4 wb = *(const float4*)&wx8[(chunk + j) * 8 + 4];
            #pragma unroll
            for (int ch = 0; ch < 4; ++ch) {
                acc[0][ch] = fmaf(wa.x, u[ch][j], acc[0][ch]);
                acc[1][ch] = fmaf(wa.y, u[ch][j], acc[1][ch]);
                acc[2][ch] = fmaf(wa.z, u[ch][j], acc[2][ch]);
                acc[3][ch] = fmaf(wa.w, u[ch][j], acc[3][ch]);
                acc[4][ch] = fmaf(wb.x, u[ch][j], acc[4][ch]);
                acc[5][ch] = fmaf(wb.y, u[ch][j], acc[5][ch]);
                acc[6][ch] = fmaf(wb.z, u[ch][j], acc[6][ch]);
            }
        }
    }

    // All 4 waves write partials; one barrier; 256-thread cooperative sum+store.
    #pragma unroll
    for (int q = 0; q < PWW; ++q)
        #pragma unroll
        for (int ch = 0; ch < 4; ++ch)
            rbuf[wig * (64 * 29) + lane * 29 + q * 4 + ch] = acc[q][ch];
    __syncthreads();

    {
        const int cc = tid;                    // thread t handles channel t
        const int lsrc = (cc >> 2) * 29 + (cc & 3);
        float* o = out + ((size_t)r * 256 + cc) * (PHH * PWW) + p * PWW;
        #pragma unroll
        for (int q = 0; q < PWW; ++q) {
            const float s = rbuf[lsrc + q * 4]
                          + rbuf[1 * (64 * 29) + lsrc + q * 4]
                          + rbuf[2 * (64 * 29) + lsrc + q * 4]
                          + rbuf[3 * (64 * 29) + lsrc + q * 4];
            o[q] = s * inv_area;
        }
    }
}

// Fallback (no scratch): one thread per output element, reads NCHW directly.
__global__ __launch_bounds__(256) void prroi_pool_nchw(
    const float* __restrict__ f, const float* __restrict__ rois,
    float* __restrict__ out, int C, int H, int W, int R)
{
    const int idx = blockIdx.x * blockDim.x + threadIdx.x;
    const int total = R * C * PHH * PWW;
    if (idx >= total) return;
    const int q = idx % PWW;
    const int p = (idx / PWW) % PHH;
    const int c = (idx / (PWW * PHH)) % C;
    const int r = idx / (PWW * PHH * C);
    const float* roi = rois + (size_t)r * 5;
    const int b = (int)roi[0];
    const float x1 = roi[1] * SPATIAL_SCALE;
    const float y1 = roi[2] * SPATIAL_SCALE;
    const float x2 = roi[3] * SPATIAL_SCALE;
    const float y2 = roi[4] * SPATIAL_SCALE;
    const float bw = fmaxf(x2 - x1, 0.0f) / (float)PWW;
    const float bh = fmaxf(y2 - y1, 0.0f) / (float)PHH;
    const float area = bw * bh;
    const float inv_area = (area > 0.0f) ? 1.0f / fmaxf(area, 1e-12f) : 0.0f;
    const float xlo = x1 + (float)q * bw, xhi = xlo + bw;
    const float ylo = y1 + (float)p * bh, yhi = ylo + bh;
    const int h0 = max(0, (int)ceilf(ylo - 1.0f));
    const int h1 = min(H - 1, (int)floorf(yhi + 1.0f));
    const int w0 = max(0, (int)ceilf(xlo - 1.0f));
    const int w1 = min(W - 1, (int)floorf(xhi + 1.0f));
    float acc = 0.0f;
    for (int h = h0; h <= h1; ++h) {
        const float wy = bin_w(ylo, yhi, (float)h);
        const float* fr = f + (((size_t)b * C + c) * H + h) * W;
        for (int w = w0; w <= w1; ++w)
            acc = fmaf(wy * bin_w(xlo, xhi, (float)w), fr[w], acc);
    }
    out[idx] = acc * inv_area;
}

extern "C" void kernel_launch(void* const* d_in, const int* in_sizes, int n_in,
                              void* d_out, int out_size, void* d_ws, size_t ws_size,
                              hipStream_t stream)
{
    const float* features = (const float*)d_in[0];
    const float* rois = (const float*)d_in[1];
    float* out = (float*)d_out;

    const int C = 256, H = 152, W = 152;
    const int N = in_sizes[0] / (C * H * W);
    const int R = in_sizes[1] / 5;

    const size_t need = (size_t)N * C * H * W * sizeof(unsigned short);
    if (ws_size >= need && C == 256) {
        unsigned short* ft = (unsigned short*)d_ws;
        const int HW = H * W;
        dim3 tgrid((HW + 31) / 32, (C + 31) / 32, N);
        transpose_nchw_nhwc_bf16<<<tgrid, dim3(32, 8), 0, stream>>>(features, ft, C, HW);
        prroi_pool_cs<<<R * PHH, 256, 0, stream>>>(ft, rois, out, H, W, R);
    } else {
        const int total = R * C * PHH * PWW;
        prroi_pool_nchw<<<(total + 255) / 256, 256, 0, stream>>>(features, rois, out, C, H, W, R);
    }
}

// Round 8
// 59.006 us; speedup vs baseline: 3.6507x; 1.0179x over previous
//
#include <hip/hip_runtime.h>

#define PHH 7
#define PWW 7
static constexpr float SPATIAL_SCALE = 0.0625f;

// Antiderivative of hat function phi(t) = max(0, 1-|t|), saturating to [0,1].
__device__ __forceinline__ float hat_int(float t) {
    t = fminf(fmaxf(t, -1.0f), 1.0f);
    float a = t + 1.0f, b = 1.0f - t;
    return (t <= 0.0f) ? 0.5f * a * a : 1.0f - 0.5f * b * b;
}

// Exact 1D integral of the hat basis at grid node g over [lo, hi].
__device__ __forceinline__ float bin_w(float lo, float hi, float g) {
    return hat_int(hi - g) - hat_int(lo - g);
}

__device__ __forceinline__ unsigned short f32_to_bf16_rne(float x) {
    unsigned int u = __float_as_uint(x);
    unsigned int r = 0x7FFFu + ((u >> 16) & 1u);
    return (unsigned short)((u + r) >> 16);
}

__device__ __forceinline__ float bf_lo(unsigned int v) {
    return __uint_as_float(v << 16);
}
__device__ __forceinline__ float bf_hi(unsigned int v) {
    return __uint_as_float(v & 0xFFFF0000u);
}

// NCHW f32 -> NHWC bf16 transpose (per n: [C, HW] -> [HW, C]), 32x32 LDS tiles.
// 47 MB read + 23.6 MB write ~= 71 MB -> ~15 us (measured r4-r7, HBM-bound).
__global__ __launch_bounds__(256) void transpose_nchw_nhwc_bf16(
    const float* __restrict__ src, unsigned short* __restrict__ dst, int C, int HW)
{
    __shared__ float tile[32][33];
    const int n = blockIdx.z;
    const int hw0 = blockIdx.x * 32;
    const int c0 = blockIdx.y * 32;
    const float* s = src + (size_t)n * C * HW;
    unsigned short* d = dst + (size_t)n * C * HW;
    const int tx = threadIdx.x, ty = threadIdx.y;
    #pragma unroll
    for (int i = ty; i < 32; i += 8) {
        int c = c0 + i, hw = hw0 + tx;
        if (c < C && hw < HW) tile[i][tx] = s[(size_t)c * HW + hw];
    }
    __syncthreads();
    #pragma unroll
    for (int i = ty; i < 32; i += 8) {
        int hw = hw0 + i, c = c0 + tx;
        if (c < C && hw < HW) d[(size_t)hw * C + c] = f32_to_bf16_rne(tile[tx][i]);
    }
}

// One block per (roi, p-bin), XCD-swizzled (roi's 7 p-blocks share an XCD's L2
// -> window/halo read reuse AND write coalescing in L2, measured r6/r7).
// 4 waves = (ch-half, col-chunk) virtual grid: wave owns 128 channels
// (lane = uint = 2 bf16 ch) x column chunks of 8 (all nh rows -> wx applied
// once per column). Ping-pong row prefetch keeps 8 loads in flight during FMA.
// 2-partial reduce (one barrier, stride-15 LDS). inv_area folded into wx.
__global__ __launch_bounds__(256) void prroi_pool_cs2(
    const unsigned short* __restrict__ ft,  // [N, H, W, 256] bf16
    const float* __restrict__ rois,         // [R, 5]
    float* __restrict__ out,                // [R, 256, PHH, PWW]
    int H, int W, int R)
{
    // Bijective XCD swizzle: consecutive blockIdx round-robin over 8 XCDs;
    // remap so each XCD owns a contiguous task chunk (whole rois).
    const int nwg = R * PHH;
    int task = (int)blockIdx.x;
    if ((nwg & 7) == 0) {
        const int cpx = nwg >> 3;
        task = (task & 7) * cpx + (task >> 3);
    }
    const int r = task / PHH;
    const int p = task % PHH;

    const int tid = threadIdx.x;
    const int wig = tid >> 6;
    const int lane = tid & 63;
    const int chHalf = wig & 1;    // channels [chHalf*128, +128)
    const int colWave = wig >> 1;  // column chunks colWave*8, step 16
    const int c0 = chHalf * 128 + lane * 2;

    const float* roi = rois + (size_t)r * 5;
    const int b = (int)roi[0];
    const float x1 = roi[1] * SPATIAL_SCALE;
    const float y1 = roi[2] * SPATIAL_SCALE;
    const float x2 = roi[3] * SPATIAL_SCALE;
    const float y2 = roi[4] * SPATIAL_SCALE;
    const float bw = fmaxf(x2 - x1, 0.0f) / (float)PWW;
    const float bh = fmaxf(y2 - y1, 0.0f) / (float)PHH;
    const float area = bw * bh;
    const float inv_area = (area > 0.0f) ? 1.0f / fmaxf(area, 1e-12f) : 0.0f;

    const float ylo = y1 + (float)p * bh;
    const float yhi = ylo + bh;
    const int h0 = max(0, (int)ceilf(ylo - 1.0f));
    const int h1 = min(H - 1, (int)floorf(yhi + 1.0f));
    const int w0 = max(0, (int)ceilf(x1 - 1.0f));
    const int w1 = min(W - 1, (int)floorf(x2 + 1.0f));
    const int nh = min(h1 - h0 + 1, 16);  // p-bin spans <= bh+3 ~ 10 rows
    const int ww = w1 - w0 + 1;           // <= W (152)
    const int wwpad = (ww + 7) & ~7;

    __shared__ float wx8[152 * 8];      // [wi][q] (q slot 7 = 0), inv_area folded
    __shared__ float wys[16];
    __shared__ float rbuf[2 * 64 * 15]; // 7.7 KB, stride 15 (odd) reduce buffer

    for (int i = tid; i < wwpad; i += 256) {
        const float g = (float)(w0 + i);
        #pragma unroll
        for (int q = 0; q < PWW; ++q) {
            const float lo = x1 + (float)q * bw;
            wx8[i * 8 + q] = (i < ww) ? bin_w(lo, lo + bw, g) * inv_area : 0.0f;
        }
        wx8[i * 8 + 7] = 0.0f;
    }
    for (int i = tid; i < nh; i += 256)
        wys[i] = bin_w(ylo, yhi, (float)(h0 + i));
    __syncthreads();

    float acc[PWW][2];
    #pragma unroll
    for (int q = 0; q < PWW; ++q) {
        acc[q][0] = 0.0f;
        acc[q][1] = 0.0f;
    }

    const size_t rowstride = (size_t)W * 256;  // u16 elements
    const unsigned short* base =
        ft + ((size_t)b * H + (size_t)h0) * rowstride + (size_t)w0 * 256 + c0;

    for (int chunk = colWave * 8; chunk < ww; chunk += 16) {
        int off[8];
        #pragma unroll
        for (int j = 0; j < 8; ++j)
            off[j] = (chunk + j < ww) ? (chunk + j) * 256 : 0;

        float u[2][8];
        #pragma unroll
        for (int j = 0; j < 8; ++j) { u[0][j] = 0.0f; u[1][j] = 0.0f; }

        auto load_row = [&](unsigned int (&v)[8], int i) {
            const unsigned short* rp = base + (size_t)i * rowstride;
            #pragma unroll
            for (int j = 0; j < 8; ++j)
                v[j] = *(const unsigned int*)(rp + off[j]);
        };
        auto fma_row = [&](const unsigned int (&v)[8], float wy) {
            #pragma unroll
            for (int j = 0; j < 8; ++j) {
                u[0][j] = fmaf(wy, bf_lo(v[j]), u[0][j]);
                u[1][j] = fmaf(wy, bf_hi(v[j]), u[1][j]);
            }
        };

        // Ping-pong: one row's 8 loads always in flight during current FMA.
        unsigned int A[8], B[8];
        load_row(A, 0);
        int i = 0;
        while (true) {
            if (i + 1 < nh) load_row(B, i + 1);
            fma_row(A, wys[i]);
            if (++i >= nh) break;
            if (i + 1 < nh) load_row(A, i + 1);
            fma_row(B, wys[i]);
            if (++i >= nh) break;
        }

        // Apply wx once per column (this virtual wave owns the column fully).
        #pragma unroll
        for (int j = 0; j < 8; ++j) {
            const float4 wa = *(const float4*)&wx8[(chunk + j) * 8];
            const float4 wb = *(const float4*)&wx8[(chunk + j) * 8 + 4];
            acc[0][0] = fmaf(wa.x, u[0][j], acc[0][0]);
            acc[0][1] = fmaf(wa.x, u[1][j], acc[0][1]);
            acc[1][0] = fmaf(wa.y, u[0][j], acc[1][0]);
            acc[1][1] = fmaf(wa.y, u[1][j], acc[1][1]);
            acc[2][0] = fmaf(wa.z, u[0][j], acc[2][0]);
            acc[2][1] = fmaf(wa.z, u[1][j], acc[2][1]);
            acc[3][0] = fmaf(wa.w, u[0][j], acc[3][0]);
            acc[3][1] = fmaf(wa.w, u[1][j], acc[3][1]);
            acc[4][0] = fmaf(wb.x, u[0][j], acc[4][0]);
            acc[4][1] = fmaf(wb.x, u[1][j], acc[4][1]);
            acc[5][0] = fmaf(wb.y, u[0][j], acc[5][0]);
            acc[5][1] = fmaf(wb.y, u[1][j], acc[5][1]);
            acc[6][0] = fmaf(wb.z, u[0][j], acc[6][0]);
            acc[6][1] = fmaf(wb.z, u[1][j], acc[6][1]);
        }
    }

    // 2-partial reduce: colWave 1 writes, one barrier, colWave 0 adds + stores.
    float* pbuf = rbuf + chHalf * (64 * 15) + lane * 15;
    if (colWave == 1) {
        #pragma unroll
        for (int q = 0; q < PWW; ++q) {
            pbuf[q * 2 + 0] = acc[q][0];
            pbuf[q * 2 + 1] = acc[q][1];
        }
    }
    __syncthreads();
    if (colWave == 0) {
        float* o = out + ((size_t)r * 256 + c0) * (PHH * PWW) + p * PWW;
        #pragma unroll
        for (int q = 0; q < PWW; ++q) {
            o[q]             = acc[q][0] + pbuf[q * 2 + 0];
            o[PHH * PWW + q] = acc[q][1] + pbuf[q * 2 + 1];
        }
    }
}

// Fallback (no scratch): one thread per output element, reads NCHW directly.
__global__ __launch_bounds__(256) void prroi_pool_nchw(
    const float* __restrict__ f, const float* __restrict__ rois,
    float* __restrict__ out, int C, int H, int W, int R)
{
    const int idx = blockIdx.x * blockDim.x + threadIdx.x;
    const int total = R * C * PHH * PWW;
    if (idx >= total) return;
    const int q = idx % PWW;
    const int p = (idx / PWW) % PHH;
    const int c = (idx / (PWW * PHH)) % C;
    const int r = idx / (PWW * PHH * C);
    const float* roi = rois + (size_t)r * 5;
    const int b = (int)roi[0];
    const float x1 = roi[1] * SPATIAL_SCALE;
    const float y1 = roi[2] * SPATIAL_SCALE;
    const float x2 = roi[3] * SPATIAL_SCALE;
    const float y2 = roi[4] * SPATIAL_SCALE;
    const float bw = fmaxf(x2 - x1, 0.0f) / (float)PWW;
    const float bh = fmaxf(y2 - y1, 0.0f) / (float)PHH;
    const float area = bw * bh;
    const float inv_area = (area > 0.0f) ? 1.0f / fmaxf(area, 1e-12f) : 0.0f;
    const float xlo = x1 + (float)q * bw, xhi = xlo + bw;
    const float ylo = y1 + (float)p * bh, yhi = ylo + bh;
    const int h0 = max(0, (int)ceilf(ylo - 1.0f));
    const int h1 = min(H - 1, (int)floorf(yhi + 1.0f));
    const int w0 = max(0, (int)ceilf(xlo - 1.0f));
    const int w1 = min(W - 1, (int)floorf(xhi + 1.0f));
    float acc = 0.0f;
    for (int h = h0; h <= h1; ++h) {
        const float wy = bin_w(ylo, yhi, (float)h);
        const float* fr = f + (((size_t)b * C + c) * H + h) * W;
        for (int w = w0; w <= w1; ++w)
            acc = fmaf(wy * bin_w(xlo, xhi, (float)w), fr[w], acc);
    }
    out[idx] = acc * inv_area;
}

extern "C" void kernel_launch(void* const* d_in, const int* in_sizes, int n_in,
                              void* d_out, int out_size, void* d_ws, size_t ws_size,
                              hipStream_t stream)
{
    const float* features = (const float*)d_in[0];
    const float* rois = (const float*)d_in[1];
    float* out = (float*)d_out;

    const int C = 256, H = 152, W = 152;
    const int N = in_sizes[0] / (C * H * W);
    const int R = in_sizes[1] / 5;

    const size_t need = (size_t)N * C * H * W * sizeof(unsigned short);
    if (ws_size >= need && C == 256) {
        unsigned short* ft = (unsigned short*)d_ws;
        const int HW = H * W;
        dim3 tgrid((HW + 31) / 32, (C + 31) / 32, N);
        transpose_nchw_nhwc_bf16<<<tgrid, dim3(32, 8), 0, stream>>>(features, ft, C, HW);
        prroi_pool_cs2<<<R * PHH, 256, 0, stream>>>(ft, rois, out, H, W, R);
    } else {
        const int total = R * C * PHH * PWW;
        prroi_pool_nchw<<<(total + 255) / 256, 256, 0, stream>>>(features, rois, out, C, H, W, R);
    }
}